// Round 12
// baseline (347.296 us; speedup 1.0000x reference)
//
#include <hip/hip_runtime.h>
#include <hip/hip_cooperative_groups.h>
#include <math.h>
#include <stdint.h>

namespace cg = cooperative_groups;

#define N_NODES 50000
#define N_EDGES 800000
#define N_TOT   850000
#define IN_F    191
#define F1      256
#define NH1     16
#define NC1     16
#define F2      24
#define NH2     8
#define NC2     3
#define KP      192          // K padded to 6*32 (191 fits)
#define MPAD    50048        // 782*64
#define NCVT_X  (MPAD * 24)
#define NCVT_W  (F1 * 24)
#define HIST_B  3125
#define EASUM_B 256
#define CVT_B   ((NCVT_X + NCVT_W) / 256)   // 4716 exactly
#define BUILD_B 256

typedef __attribute__((ext_vector_type(8))) short bf16x8;
typedef __attribute__((ext_vector_type(4))) float f32x4;

#define GLL16(g, s) __builtin_amdgcn_global_load_lds( \
    (const __attribute__((address_space(1))) void*)(g), \
    (__attribute__((address_space(3))) void*)(s), 16, 0, 0)

__device__ __forceinline__ float lrelu(float x) { return x > 0.f ? x : 0.2f * x; }

__device__ __forceinline__ uint16_t f2bf1(float f) {
    uint32_t u = __float_as_uint(f);
    return (uint16_t)((u + 0x7fffu + ((u >> 16) & 1u)) >> 16);
}
__device__ __forceinline__ void bf2f2(uint32_t u, float* lo, float* hi) {
    *lo = __uint_as_float(u << 16);
    *hi = __uint_as_float(u & 0xffff0000u);
}

// ---------------- fused pre-pass: {histogram | easum | cvt} by block range ----------------
__global__ void k_pre(const int* __restrict__ ei, const float* __restrict__ ea,
                      const float* __restrict__ x, const float* __restrict__ W1,
                      int* counts, float* __restrict__ part,
                      uint16_t* __restrict__ xh, uint16_t* __restrict__ wht) {
    int b = blockIdx.x, t = threadIdx.x;
    if (b < HIST_B) {
        int e = b * 256 + t;
        if (e < N_EDGES) atomicAdd(&counts[ei[N_EDGES + e]], 1);
    } else if (b < HIST_B + EASUM_B) {
        __shared__ float wsums[4];
        int eb = b - HIST_B;
        float v = 0.f;
        for (int e = eb * 256 + t; e < N_EDGES; e += 256 * 256) v += ea[e];
        #pragma unroll
        for (int off = 32; off >= 1; off >>= 1) v += __shfl_xor(v, off);
        if ((t & 63) == 0) wsums[t >> 6] = v;
        __syncthreads();
        if (t == 0) part[eb] = wsums[0] + wsums[1] + wsums[2] + wsums[3];
    } else {
        int idx = (b - HIST_B - EASUM_B) * 256 + t;
        if (idx < NCVT_X) {
            int row = idx / 24, kw = idx - row * 24;
            int k0 = kw * 8;
            uint16_t hv[8];
            #pragma unroll
            for (int j = 0; j < 8; j++) {
                int k = k0 + j;
                float v = (row < N_NODES && k < IN_F) ? x[(size_t)row * IN_F + k] : 0.f;
                hv[j] = f2bf1(v);
            }
            *(uint4*)(xh + (size_t)row * KP + k0) = *(const uint4*)hv;
        } else {
            int id2 = idx - NCVT_X;
            int col = id2 / 24, kw = id2 - col * 24;
            int k0 = kw * 8;
            uint16_t hv[8];
            #pragma unroll
            for (int j = 0; j < 8; j++) {
                int k = k0 + j;
                float v = (k < IN_F) ? W1[(size_t)k * F1 + col] : 0.f;
                hv[j] = f2bf1(v);
            }
            *(uint4*)(wht + (size_t)col * KP + k0) = *(const uint4*)hv;
        }
    }
}

// ---------------- cooperative CSR build: scan (2 phases) + wedot + scatter ----------------
__global__ __launch_bounds__(1024) void k_build(const int* __restrict__ counts,
        int* rowptr, int* cursor, int* bsums,
        const float* __restrict__ We1, const float* __restrict__ ae1,
        const float* __restrict__ We2, const float* __restrict__ ae2,
        const float* __restrict__ part, float* scalars,
        const int* __restrict__ ei, const float* __restrict__ ea,
        uint32_t* __restrict__ csr) {
    cg::grid_group grid = cg::this_grid();
    const int b = blockIdx.x, t = threadIdx.x;
    // ---- phase 1: per-chunk scan (blocks 0..48) | wedot + ea_mean (block 49)
    if (b < 49) {
        __shared__ int wsum[16];
        int lane = t & 63, w = t >> 6;
        int i = b * 1024 + t;
        int v = (i < N_NODES) ? counts[i] + 1 : 0;   // +1 = self loop
        int incl = v;
        #pragma unroll
        for (int off = 1; off < 64; off <<= 1) {
            int u = __shfl_up(incl, off);
            if (lane >= off) incl += u;
        }
        if (lane == 63) wsum[w] = incl;
        __syncthreads();
        int woff = 0;
        #pragma unroll
        for (int k = 0; k < 16; k++) woff += (k < w) ? wsum[k] : 0;
        if (i < N_NODES) rowptr[i] = woff + incl - v;   // within-chunk exclusive
        if (t == 1023) bsums[b] = woff + incl;
    } else if (b == 49 && t < 64) {
        if (t < NH1) {
            float s = 0.f;
            for (int c = 0; c < NC1; c++) s += We1[t * NC1 + c] * ae1[t * NC1 + c];
            scalars[1 + t] = s;
        } else if (t < NH1 + NH2) {
            int h = t - NH1;
            float s = 0.f;
            for (int c = 0; c < NC2; c++) s += We2[h * NC2 + c] * ae2[h * NC2 + c];
            scalars[17 + h] = s;
        }
        float v = part[t * 4] + part[t * 4 + 1] + part[t * 4 + 2] + part[t * 4 + 3];
        #pragma unroll
        for (int off = 32; off >= 1; off >>= 1) v += __shfl_xor(v, off);
        if (t == 0) scalars[0] = v / (float)N_EDGES;   // ea_mean
    }
    grid.sync();
    // ---- phase 2: add chunk prefix (each block sums its 0..b-1 bsums locally)
    if (b < 49) {
        int off = 0;
        for (int k = 0; k < b; k++) off += bsums[k];
        int i = b * 1024 + t;
        if (i < N_NODES) {
            int r = rowptr[i] + off;
            rowptr[i] = r;
            cursor[i] = r;
        }
        if (b == 48 && t == 1023) rowptr[N_NODES] = off + bsums[48];
    }
    grid.sync();
    // ---- phase 3: grid-stride scatter into 4B packed CSR (u16 src | bf16 ea)
    float eam = scalars[0];
    for (int i = b * 1024 + t; i < N_TOT; i += BUILD_B * 1024) {
        if (i < N_EDGES) {
            int s = ei[i], d = ei[N_EDGES + i];
            int pos = atomicAdd(&cursor[d], 1);
            csr[pos] = (uint32_t)s | ((uint32_t)f2bf1(ea[i]) << 16);
        } else {
            int n = i - N_EDGES;
            int pos = atomicAdd(&cursor[n], 1);
            csr[pos] = (uint32_t)n | ((uint32_t)f2bf1(eam) << 16);
        }
    }
}

// ---------------- GEMM1 via MFMA: 64x256 tile (x read once) + fused alphas1 ----------------
// LDS: staging (A 4KB + B 16KB) reused as 32KB fp->bf16 row stage for the alphas epilogue.
__global__ __launch_bounds__(256) void k_gemm1_mfma(const uint16_t* __restrict__ xh,
        const uint16_t* __restrict__ wht, const float* __restrict__ a_src,
        const float* __restrict__ a_dst, uint16_t* __restrict__ xl1b,
        float* __restrict__ asrc1, float* __restrict__ adst1) {
    __shared__ uint16_t smem[64 * 256];     // 32 KiB
    uint16_t* ldsA = smem;                  // 4 frags * 512
    uint16_t* ldsB = smem + 4 * 512;        // 16 frags * 512  (total 20KB < 32KB)
    const int t = threadIdx.x;
    const int l = t & 63, w = t >> 6;
    const int m0 = blockIdx.x * 64;
    const int lr = l & 15, lk = l >> 4;

    f32x4 acc[4][4];
    #pragma unroll
    for (int i = 0; i < 4; i++)
        #pragma unroll
        for (int j = 0; j < 4; j++)
            acc[i][j] = (f32x4){0.f, 0.f, 0.f, 0.f};

    for (int ks = 0; ks < 6; ks++) {
        const int kb = ks * 32 + lk * 8;
        #pragma unroll
        for (int ii = 0; ii < 5; ii++) {
            const int idx = w * 5 + ii;      // 0..19: 4 A-frags then 16 B-frags
            if (idx < 4) {
                const uint16_t* src = xh + (size_t)(m0 + idx * 16 + lr) * KP + kb;
                GLL16(src, ldsA + idx * 512);
            } else {
                const int g = idx - 4;
                const uint16_t* src = wht + (size_t)(g * 16 + lr) * KP + kb;
                GLL16(src, ldsB + g * 512);
            }
        }
        __syncthreads();
        bf16x8 ah[4];
        #pragma unroll
        for (int i = 0; i < 4; i++)
            ah[i] = *(const bf16x8*)(ldsA + (i * 64 + l) * 8);
        #pragma unroll
        for (int j = 0; j < 4; j++) {
            const int g = w * 4 + j;
            bf16x8 bh = *(const bf16x8*)(ldsB + (g * 64 + l) * 8);
            #pragma unroll
            for (int i = 0; i < 4; i++)
                acc[i][j] = __builtin_amdgcn_mfma_f32_16x16x32_bf16(ah[i], bh, acc[i][j], 0, 0, 0);
        }
        __syncthreads();
    }
    // epilogue: write xl1b (bf16) + stage rows into LDS for the alphas dot
    #pragma unroll
    for (int i = 0; i < 4; i++) {
        #pragma unroll
        for (int r = 0; r < 4; r++) {
            const int lrow = i * 16 + lk * 4 + r;
            const int gm = m0 + lrow;
            #pragma unroll
            for (int j = 0; j < 4; j++) {
                const int gn = (w * 4 + j) * 16 + lr;
                uint16_t bv = f2bf1(acc[i][j][r]);
                smem[lrow * 256 + gn] = bv;
                if (gm < N_NODES) xl1b[(size_t)gm * F1 + gn] = bv;
            }
        }
    }
    __syncthreads();
    // alphas: 64 rows x 16 heads = 1024 items, 4 per thread
    #pragma unroll
    for (int q = 0; q < 4; q++) {
        int item = q * 256 + t;
        int row = item >> 4, h = item & 15;
        int gm = m0 + row;
        if (gm < N_NODES) {
            const uint4* rp = (const uint4*)(smem + row * 256 + h * 16);
            uint4 u0 = rp[0], u1 = rp[1];
            uint32_t us[8] = {u0.x, u0.y, u0.z, u0.w, u1.x, u1.y, u1.z, u1.w};
            float as = 0.f, ad = 0.f;
            #pragma unroll
            for (int p = 0; p < 8; p++) {
                float lo, hi;
                bf2f2(us[p], &lo, &hi);
                as += lo * a_src[h * 16 + 2 * p] + hi * a_src[h * 16 + 2 * p + 1];
                ad += lo * a_dst[h * 16 + 2 * p] + hi * a_dst[h * 16 + 2 * p + 1];
            }
            asrc1[gm * 16 + h] = as;
            adst1[gm * 16 + h] = ad;
        }
    }
}

// ---------------- aggregation layer 1 (locked R8 form: 4 edge-groups x 32B/lane) ----------------
__global__ __launch_bounds__(256) void k_agg1(const int* __restrict__ rowptr,
        const uint32_t* __restrict__ csr,
        const uint16_t* __restrict__ xl1b, const float* __restrict__ asrc,
        const float* __restrict__ adst, const float* __restrict__ scalars,
        const float* __restrict__ b1, uint16_t* __restrict__ h1b) {
    int node = blockIdx.x * 4 + (threadIdx.x >> 6);
    int lane = threadIdx.x & 63;
    int eg = lane >> 4, h = lane & 15;
    int r0 = rowptr[node], r1 = rowptr[node + 1];
    float ad = adst[node * 16 + h];
    float wd = scalars[1 + h];
    float den = 0.f;
    float acc[16];
    #pragma unroll
    for (int c = 0; c < 16; c++) acc[c] = 0.f;
    for (int j = r0 + eg; j < r1; j += 4) {
        uint32_t pk = csr[j];
        int s = (int)(pk & 0xFFFFu);
        float eav = __uint_as_float(pk & 0xFFFF0000u);
        float a = lrelu(asrc[s * 16 + h] + ad + eav * wd);
        float wgt = __expf(a);           // no max-shift: logits bounded, fp32 safe
        den += wgt;
        const uint4* xp = (const uint4*)(xl1b + (size_t)s * F1 + h * 16);
        uint4 u0 = xp[0], u1 = xp[1];
        float lo, hi;
        bf2f2(u0.x, &lo, &hi); acc[0] += wgt * lo;  acc[1] += wgt * hi;
        bf2f2(u0.y, &lo, &hi); acc[2] += wgt * lo;  acc[3] += wgt * hi;
        bf2f2(u0.z, &lo, &hi); acc[4] += wgt * lo;  acc[5] += wgt * hi;
        bf2f2(u0.w, &lo, &hi); acc[6] += wgt * lo;  acc[7] += wgt * hi;
        bf2f2(u1.x, &lo, &hi); acc[8] += wgt * lo;  acc[9] += wgt * hi;
        bf2f2(u1.y, &lo, &hi); acc[10] += wgt * lo; acc[11] += wgt * hi;
        bf2f2(u1.z, &lo, &hi); acc[12] += wgt * lo; acc[13] += wgt * hi;
        bf2f2(u1.w, &lo, &hi); acc[14] += wgt * lo; acc[15] += wgt * hi;
    }
    den += __shfl_xor(den, 16);
    den += __shfl_xor(den, 32);
    float inv = 1.f / (den + 1e-16f);
    #pragma unroll
    for (int c = 0; c < 16; c++) {
        acc[c] += __shfl_xor(acc[c], 16);
        acc[c] += __shfl_xor(acc[c], 32);
    }
    if (eg == 0) {
        uint32_t pk[8];
        #pragma unroll
        for (int q = 0; q < 8; q++) {
            float v0 = acc[2 * q] * inv + b1[h * 16 + 2 * q];
            float v1 = acc[2 * q + 1] * inv + b1[h * 16 + 2 * q + 1];
            v0 = v0 > 0.f ? v0 : expm1f(v0);   // ELU
            v1 = v1 > 0.f ? v1 : expm1f(v1);
            pk[q] = (uint32_t)f2bf1(v0) | ((uint32_t)f2bf1(v1) << 16);
        }
        uint4* op = (uint4*)(h1b + (size_t)node * F1 + h * 16);
        op[0] = make_uint4(pk[0], pk[1], pk[2], pk[3]);
        op[1] = make_uint4(pk[4], pk[5], pk[6], pk[7]);
    }
}

// ---------------- fused layer2: xl2 = h1 @ W2 (+pad) AND alpha_src2/alpha_dst2 ----------------
__global__ __launch_bounds__(256) void k_layer2(const uint16_t* __restrict__ h1b,
        const float* __restrict__ W2, const float* __restrict__ a_src,
        const float* __restrict__ a_dst, uint16_t* __restrict__ xl2b,
        float* __restrict__ asrc, float* __restrict__ adst) {
    __shared__ float W2s[F2][258];   // [col][k], padded stride
    int t = threadIdx.x;
    for (int i = t; i < 256 * F2; i += 256) {
        int k = i / F2, c = i - k * F2;
        W2s[c][k] = W2[i];
    }
    __syncthreads();
    int idx = blockIdx.x * 256 + t;
    if (idx >= N_NODES * NH2) return;
    int n = idx >> 3, h = idx & 7;
    int c0 = h * 3;
    const uint4* hp = (const uint4*)(h1b + (size_t)n * F1);
    float a0 = 0.f, a1 = 0.f, a2 = 0.f;
    #pragma unroll 4
    for (int q = 0; q < 32; q++) {
        uint4 u = hp[q];
        float f[8];
        bf2f2(u.x, &f[0], &f[1]);
        bf2f2(u.y, &f[2], &f[3]);
        bf2f2(u.z, &f[4], &f[5]);
        bf2f2(u.w, &f[6], &f[7]);
        #pragma unroll
        for (int j = 0; j < 8; j++) {
            int k = q * 8 + j;
            a0 += f[j] * W2s[c0][k];
            a1 += f[j] * W2s[c0 + 1][k];
            a2 += f[j] * W2s[c0 + 2][k];
        }
    }
    uint2 pk;
    pk.x = (uint32_t)f2bf1(a0) | ((uint32_t)f2bf1(a1) << 16);
    pk.y = (uint32_t)f2bf1(a2);
    *(uint2*)(xl2b + (size_t)idx * 4) = pk;
    asrc[idx] = a0 * a_src[h * 3 + 0] + a1 * a_src[h * 3 + 1] + a2 * a_src[h * 3 + 2];
    adst[idx] = a0 * a_dst[h * 3 + 0] + a1 * a_dst[h * 3 + 1] + a2 * a_dst[h * 3 + 2];
}

// ---------------- aggregation layer 2 (wave per node, 4B CSR) ----------------
__global__ __launch_bounds__(256) void k_agg2(const int* __restrict__ rowptr,
        const uint32_t* __restrict__ csr,
        const uint16_t* __restrict__ xl2b, const float* __restrict__ asrc,
        const float* __restrict__ adst, const float* __restrict__ scalars,
        const float* __restrict__ b2, float* __restrict__ out) {
    int node = blockIdx.x * 4 + (threadIdx.x >> 6);
    int lane = threadIdx.x & 63;
    int eg = lane >> 3, h = lane & 7;
    int r0 = rowptr[node], r1 = rowptr[node + 1];
    float ad = adst[node * 8 + h];
    float wd = scalars[17 + h];
    float den = 0.f, a0 = 0.f, a1 = 0.f, a2 = 0.f;
    for (int j = r0 + eg; j < r1; j += 8) {
        uint32_t pk = csr[j];
        int s = (int)(pk & 0xFFFFu);
        float eav = __uint_as_float(pk & 0xFFFF0000u);
        float a = lrelu(asrc[s * 8 + h] + ad + eav * wd);
        float wgt = __expf(a);
        den += wgt;
        const uint2* xp = (const uint2*)(xl2b + ((size_t)s * 8 + h) * 4);
        uint2 u = xp[0];
        float x0, x1, x2, dummy;
        bf2f2(u.x, &x0, &x1);
        bf2f2(u.y, &x2, &dummy);
        a0 += wgt * x0;
        a1 += wgt * x1;
        a2 += wgt * x2;
    }
    den += __shfl_xor(den, 8); den += __shfl_xor(den, 16); den += __shfl_xor(den, 32);
    float inv = 1.f / (den + 1e-16f);
    a0 += __shfl_xor(a0, 8); a0 += __shfl_xor(a0, 16); a0 += __shfl_xor(a0, 32);
    a1 += __shfl_xor(a1, 8); a1 += __shfl_xor(a1, 16); a1 += __shfl_xor(a1, 32);
    a2 += __shfl_xor(a2, 8); a2 += __shfl_xor(a2, 16); a2 += __shfl_xor(a2, 32);
    a0 *= inv; a1 *= inv; a2 *= inv;
    a0 += __shfl_xor(a0, 1); a0 += __shfl_xor(a0, 2); a0 += __shfl_xor(a0, 4);
    a1 += __shfl_xor(a1, 1); a1 += __shfl_xor(a1, 2); a1 += __shfl_xor(a1, 4);
    a2 += __shfl_xor(a2, 1); a2 += __shfl_xor(a2, 2); a2 += __shfl_xor(a2, 4);
    if (lane == 0) {
        float v0 = a0 * 0.125f + b2[0];
        float v1 = a1 * 0.125f + b2[1];
        float v2 = a2 * 0.125f + b2[2];
        out[node * 3 + 0] = v0 > 0.f ? v0 : expm1f(v0);
        out[node * 3 + 1] = v1 > 0.f ? v1 : expm1f(v1);
        out[node * 3 + 2] = v2 > 0.f ? v2 : expm1f(v2);
    }
}

extern "C" void kernel_launch(void* const* d_in, const int* in_sizes, int n_in,
                              void* d_out, int out_size, void* d_ws, size_t ws_size,
                              hipStream_t stream) {
    const float* x       = (const float*)d_in[0];
    const int*   ei      = (const int*)d_in[1];
    const float* ea      = (const float*)d_in[2];
    const float* W1      = (const float*)d_in[3];
    const float* We1     = (const float*)d_in[4];
    const float* a_src1  = (const float*)d_in[5];
    const float* a_dst1  = (const float*)d_in[6];
    const float* a_edge1 = (const float*)d_in[7];
    const float* b1      = (const float*)d_in[8];
    const float* W2      = (const float*)d_in[9];
    const float* We2     = (const float*)d_in[10];
    const float* a_src2  = (const float*)d_in[11];
    const float* a_dst2  = (const float*)d_in[12];
    const float* a_edge2 = (const float*)d_in[13];
    const float* b2      = (const float*)d_in[14];
    float* out = (float*)d_out;

    char* ws = (char*)d_ws;
    size_t off = 0;
    auto alloc = [&](size_t nbytes) -> void* {
        void* p = ws + off;
        off = (off + nbytes + 255) & ~(size_t)255;
        return p;
    };
    uint16_t* xl1b  = (uint16_t*)alloc((size_t)N_NODES * F1 * 2);
    uint16_t* h1b   = (uint16_t*)alloc((size_t)N_NODES * F1 * 2);
    float* asrc1    = (float*)alloc((size_t)N_NODES * NH1 * 4);
    float* adst1    = (float*)alloc((size_t)N_NODES * NH1 * 4);
    uint16_t* xl2b  = (uint16_t*)alloc((size_t)N_NODES * 32 * 2);
    float* asrc2    = (float*)alloc((size_t)N_NODES * NH2 * 4);
    float* adst2    = (float*)alloc((size_t)N_NODES * NH2 * 4);
    int*   counts   = (int*)alloc((size_t)N_NODES * 4);
    int*   rowptr   = (int*)alloc((size_t)(N_NODES + 1) * 4);
    int*   cursor   = (int*)alloc((size_t)N_NODES * 4);
    int*   bsums    = (int*)alloc(64 * 4);
    uint32_t* csr   = (uint32_t*)alloc((size_t)N_TOT * 4);
    float* scalars  = (float*)alloc(128);
    float* part     = (float*)alloc(256 * 4);
    uint16_t* wht   = (uint16_t*)alloc((size_t)F1 * KP * 2);
    uint16_t* xh    = (uint16_t*)alloc((size_t)MPAD * KP * 2);

    hipMemsetAsync(counts, 0, (size_t)N_NODES * 4, stream);
    hipLaunchKernelGGL(k_pre, dim3(HIST_B + EASUM_B + CVT_B), dim3(256), 0, stream,
                       ei, ea, x, W1, counts, part, xh, wht);
    {
        void* args[] = {(void*)&counts, (void*)&rowptr, (void*)&cursor, (void*)&bsums,
                        (void*)&We1, (void*)&a_edge1, (void*)&We2, (void*)&a_edge2,
                        (void*)&part, (void*)&scalars, (void*)&ei, (void*)&ea,
                        (void*)&csr};
        hipLaunchCooperativeKernel((void*)k_build, dim3(BUILD_B), dim3(1024),
                                   args, 0, stream);
    }
    hipLaunchKernelGGL(k_gemm1_mfma, dim3(MPAD / 64), dim3(256), 0, stream,
                       xh, wht, a_src1, a_dst1, xl1b, asrc1, adst1);
    hipLaunchKernelGGL(k_agg1, dim3(N_NODES / 4), dim3(256), 0, stream,
                       rowptr, csr, xl1b, asrc1, adst1, scalars, b1, h1b);
    hipLaunchKernelGGL(k_layer2, dim3((N_NODES * NH2 + 255) / 256), dim3(256), 0, stream,
                       h1b, W2, a_src2, a_dst2, xl2b, asrc2, adst2);
    hipLaunchKernelGGL(k_agg2, dim3(N_NODES / 4), dim3(256), 0, stream,
                       rowptr, csr, xl2b, asrc2, adst2, scalars, b2, out);
}

// Round 13
// 305.961 us; speedup vs baseline: 1.1351x; 1.1351x over previous
//
#include <hip/hip_runtime.h>
#include <math.h>
#include <stdint.h>

#define N_NODES 50000
#define N_EDGES 800000
#define N_TOT   850000
#define IN_F    191
#define F1      256
#define NH1     16
#define NC1     16
#define F2      24
#define NH2     8
#define NC2     3
#define KP      192          // K padded to 6*32 (191 fits)
#define MPAD    50048        // 782*64
#define NCVT_X  (MPAD * 24)
#define NCVT_W  (F1 * 24)
#define HIST_B  3125
#define EASUM_B 256
#define CVT_B   ((NCVT_X + NCVT_W) / 256)   // 4716 exactly

typedef __attribute__((ext_vector_type(8))) short bf16x8;
typedef __attribute__((ext_vector_type(4))) float f32x4;

#define GLL16(g, s) __builtin_amdgcn_global_load_lds( \
    (const __attribute__((address_space(1))) void*)(g), \
    (__attribute__((address_space(3))) void*)(s), 16, 0, 0)

__device__ __forceinline__ float lrelu(float x) { return x > 0.f ? x : 0.2f * x; }

__device__ __forceinline__ uint16_t f2bf1(float f) {
    uint32_t u = __float_as_uint(f);
    return (uint16_t)((u + 0x7fffu + ((u >> 16) & 1u)) >> 16);
}
__device__ __forceinline__ void bf2f2(uint32_t u, float* lo, float* hi) {
    *lo = __uint_as_float(u << 16);
    *hi = __uint_as_float(u & 0xffff0000u);
}
__device__ __forceinline__ float bf2f(uint16_t v) {
    return __uint_as_float((uint32_t)v << 16);
}

// ---------------- fused pre-pass: {histogram | easum | cvt} by block range ----------------
__global__ void k_pre(const int* __restrict__ ei, const float* __restrict__ ea,
                      const float* __restrict__ x, const float* __restrict__ W1,
                      int* counts, float* __restrict__ part,
                      uint16_t* __restrict__ xh, uint16_t* __restrict__ wht) {
    int b = blockIdx.x, t = threadIdx.x;
    if (b < HIST_B) {
        int e = b * 256 + t;
        if (e < N_EDGES) atomicAdd(&counts[ei[N_EDGES + e]], 1);
    } else if (b < HIST_B + EASUM_B) {
        __shared__ float wsums[4];
        int eb = b - HIST_B;
        float v = 0.f;
        for (int e = eb * 256 + t; e < N_EDGES; e += 256 * 256) v += ea[e];
        #pragma unroll
        for (int off = 32; off >= 1; off >>= 1) v += __shfl_xor(v, off);
        if ((t & 63) == 0) wsums[t >> 6] = v;
        __syncthreads();
        if (t == 0) part[eb] = wsums[0] + wsums[1] + wsums[2] + wsums[3];
    } else {
        int idx = (b - HIST_B - EASUM_B) * 256 + t;
        if (idx < NCVT_X) {
            int row = idx / 24, kw = idx - row * 24;
            int k0 = kw * 8;
            uint16_t hv[8];
            #pragma unroll
            for (int j = 0; j < 8; j++) {
                int k = k0 + j;
                float v = (row < N_NODES && k < IN_F) ? x[(size_t)row * IN_F + k] : 0.f;
                hv[j] = f2bf1(v);
            }
            *(uint4*)(xh + (size_t)row * KP + k0) = *(const uint4*)hv;
        } else {
            int id2 = idx - NCVT_X;
            int col = id2 / 24, kw = id2 - col * 24;
            int k0 = kw * 8;
            uint16_t hv[8];
            #pragma unroll
            for (int j = 0; j < 8; j++) {
                int k = k0 + j;
                float v = (k < IN_F) ? W1[(size_t)k * F1 + col] : 0.f;
                hv[j] = f2bf1(v);
            }
            *(uint4*)(wht + (size_t)col * KP + k0) = *(const uint4*)hv;
        }
    }
}

// ---------------- scan stage 1 (blocks 0..48) + wedot (block 49) ----------------
__global__ __launch_bounds__(1024) void k_scan1(const int* __restrict__ counts,
        int* rowptr, int* bsums,
        const float* __restrict__ We1, const float* __restrict__ ae1,
        const float* __restrict__ We2, const float* __restrict__ ae2,
        const float* __restrict__ part, float* scalars) {
    int b = blockIdx.x, t = threadIdx.x;
    if (b == 49) {
        if (t < 64) {
            if (t < NH1) {
                float s = 0.f;
                for (int c = 0; c < NC1; c++) s += We1[t * NC1 + c] * ae1[t * NC1 + c];
                scalars[1 + t] = s;
            } else if (t < NH1 + NH2) {
                int h = t - NH1;
                float s = 0.f;
                for (int c = 0; c < NC2; c++) s += We2[h * NC2 + c] * ae2[h * NC2 + c];
                scalars[17 + h] = s;
            }
            float v = part[t * 4] + part[t * 4 + 1] + part[t * 4 + 2] + part[t * 4 + 3];
            #pragma unroll
            for (int off = 32; off >= 1; off >>= 1) v += __shfl_xor(v, off);
            if (t == 0) scalars[0] = v / (float)N_EDGES;   // ea_mean
        }
        return;
    }
    __shared__ int wsum[16];
    int lane = t & 63, w = t >> 6;
    int i = b * 1024 + t;
    int v = (i < N_NODES) ? counts[i] + 1 : 0;   // +1 = self loop
    int incl = v;
    #pragma unroll
    for (int off = 1; off < 64; off <<= 1) {
        int u = __shfl_up(incl, off);
        if (lane >= off) incl += u;
    }
    if (lane == 63) wsum[w] = incl;
    __syncthreads();
    int woff = 0;
    #pragma unroll
    for (int k = 0; k < 16; k++) woff += (k < w) ? wsum[k] : 0;
    if (i < N_NODES) rowptr[i] = woff + incl - v;
    if (t == 1023) bsums[b] = woff + incl;
}

// ---------------- scan stage 2: global prefix + SELF-LOOP placement ----------------
__global__ __launch_bounds__(1024) void k_scan2(int* rowptr, int* cursor,
                                                const int* __restrict__ bsums,
                                                const float* __restrict__ scalars,
                                                uint32_t* __restrict__ csr) {
    __shared__ int off_s;
    int b = blockIdx.x, t = threadIdx.x;
    if (t == 0) {
        int o = 0;
        for (int k = 0; k < b; k++) o += bsums[k];
        off_s = o;
        if (b == 48) rowptr[N_NODES] = o + bsums[48];
    }
    __syncthreads();
    uint32_t loop_ea = (uint32_t)f2bf1(scalars[0]) << 16;
    int i = b * 1024 + t;
    if (i < N_NODES) {
        int r = rowptr[i] + off_s;
        rowptr[i] = r;
        cursor[i] = r + 1;                       // edges go after the self loop
        csr[r] = (uint32_t)i | loop_ea;          // self loop placed here
    }
}

// ---------------- scatter real edges into 4B packed CSR (u16 src | bf16 ea) ----------------
__global__ void k_scatter(const int* __restrict__ ei, const float* __restrict__ ea,
                          int* cursor, uint32_t* __restrict__ csr) {
    int i = blockIdx.x * blockDim.x + threadIdx.x;
    if (i < N_EDGES) {
        int s = ei[i], d = ei[N_EDGES + i];
        int pos = atomicAdd(&cursor[d], 1);
        csr[pos] = (uint32_t)s | ((uint32_t)f2bf1(ea[i]) << 16);
    }
}

// ---------------- GEMM1 via MFMA: 64x256 tile (x read once) + fused alphas1 ----------------
__global__ __launch_bounds__(256) void k_gemm1_mfma(const uint16_t* __restrict__ xh,
        const uint16_t* __restrict__ wht, const float* __restrict__ a_src,
        const float* __restrict__ a_dst, uint16_t* __restrict__ xl1b,
        float* __restrict__ asrc1, float* __restrict__ adst1) {
    __shared__ uint16_t smem[64 * 256];     // 32 KiB
    uint16_t* ldsA = smem;                  // 4 frags * 512
    uint16_t* ldsB = smem + 4 * 512;        // 16 frags * 512
    const int t = threadIdx.x;
    const int l = t & 63, w = t >> 6;
    const int m0 = blockIdx.x * 64;
    const int lr = l & 15, lk = l >> 4;

    f32x4 acc[4][4];
    #pragma unroll
    for (int i = 0; i < 4; i++)
        #pragma unroll
        for (int j = 0; j < 4; j++)
            acc[i][j] = (f32x4){0.f, 0.f, 0.f, 0.f};

    for (int ks = 0; ks < 6; ks++) {
        const int kb = ks * 32 + lk * 8;
        #pragma unroll
        for (int ii = 0; ii < 5; ii++) {
            const int idx = w * 5 + ii;      // 0..19: 4 A-frags then 16 B-frags
            if (idx < 4) {
                const uint16_t* src = xh + (size_t)(m0 + idx * 16 + lr) * KP + kb;
                GLL16(src, ldsA + idx * 512);
            } else {
                const int g = idx - 4;
                const uint16_t* src = wht + (size_t)(g * 16 + lr) * KP + kb;
                GLL16(src, ldsB + g * 512);
            }
        }
        __syncthreads();
        bf16x8 ah[4];
        #pragma unroll
        for (int i = 0; i < 4; i++)
            ah[i] = *(const bf16x8*)(ldsA + (i * 64 + l) * 8);
        #pragma unroll
        for (int j = 0; j < 4; j++) {
            const int g = w * 4 + j;
            bf16x8 bh = *(const bf16x8*)(ldsB + (g * 64 + l) * 8);
            #pragma unroll
            for (int i = 0; i < 4; i++)
                acc[i][j] = __builtin_amdgcn_mfma_f32_16x16x32_bf16(ah[i], bh, acc[i][j], 0, 0, 0);
        }
        __syncthreads();
    }
    // epilogue: write xl1b (bf16) + stage rows into LDS for the alphas dot
    #pragma unroll
    for (int i = 0; i < 4; i++) {
        #pragma unroll
        for (int r = 0; r < 4; r++) {
            const int lrow = i * 16 + lk * 4 + r;
            const int gm = m0 + lrow;
            #pragma unroll
            for (int j = 0; j < 4; j++) {
                const int gn = (w * 4 + j) * 16 + lr;
                uint16_t bv = f2bf1(acc[i][j][r]);
                smem[lrow * 256 + gn] = bv;
                if (gm < N_NODES) xl1b[(size_t)gm * F1 + gn] = bv;
            }
        }
    }
    __syncthreads();
    // alphas: 64 rows x 16 heads = 1024 items, 4 per thread
    #pragma unroll
    for (int q = 0; q < 4; q++) {
        int item = q * 256 + t;
        int row = item >> 4, h = item & 15;
        int gm = m0 + row;
        if (gm < N_NODES) {
            const uint4* rp = (const uint4*)(smem + row * 256 + h * 16);
            uint4 u0 = rp[0], u1 = rp[1];
            uint32_t us[8] = {u0.x, u0.y, u0.z, u0.w, u1.x, u1.y, u1.z, u1.w};
            float as = 0.f, ad = 0.f;
            #pragma unroll
            for (int p = 0; p < 8; p++) {
                float lo, hi;
                bf2f2(us[p], &lo, &hi);
                as += lo * a_src[h * 16 + 2 * p] + hi * a_src[h * 16 + 2 * p + 1];
                ad += lo * a_dst[h * 16 + 2 * p] + hi * a_dst[h * 16 + 2 * p + 1];
            }
            asrc1[gm * 16 + h] = as;
            adst1[gm * 16 + h] = ad;
        }
    }
}

// ---------------- agg1 (locked R8 gather) + FUSED layer2 epilogue ----------------
// h1 rows round-trip through LDS (bf16-rounded, same numerics as the old h1b path);
// W2 staged bf16 in LDS (12.5KB). No h1b materialization.
__global__ __launch_bounds__(256) void k_agg1(const int* __restrict__ rowptr,
        const uint32_t* __restrict__ csr,
        const uint16_t* __restrict__ xl1b, const float* __restrict__ asrc,
        const float* __restrict__ adst, const float* __restrict__ scalars,
        const float* __restrict__ b1, const float* __restrict__ W2,
        const float* __restrict__ a_src2, const float* __restrict__ a_dst2,
        uint16_t* __restrict__ xl2b, float* __restrict__ asrc2,
        float* __restrict__ adst2) {
    __shared__ uint16_t W2s[F2][260];       // bf16 [col][k], 12.2KB
    __shared__ uint32_t rowbuf[4][128];     // 4 nodes x 256 bf16 (as u32 pairs), 2KB
    int tid = threadIdx.x;
    for (int i = tid; i < 256 * F2; i += 256) {
        int k = i / F2, c = i - k * F2;
        W2s[c][k] = f2bf1(W2[i]);
    }
    int node = blockIdx.x * 4 + (tid >> 6);
    int lane = tid & 63;
    int eg = lane >> 4, h = lane & 15;
    int r0 = rowptr[node], r1 = rowptr[node + 1];
    float ad = adst[node * 16 + h];
    float wd = scalars[1 + h];
    float den = 0.f;
    float acc[16];
    #pragma unroll
    for (int c = 0; c < 16; c++) acc[c] = 0.f;
    for (int j = r0 + eg; j < r1; j += 4) {
        uint32_t pk = csr[j];
        int s = (int)(pk & 0xFFFFu);
        float eav = __uint_as_float(pk & 0xFFFF0000u);
        float a = lrelu(asrc[s * 16 + h] + ad + eav * wd);
        float wgt = __expf(a);           // no max-shift: logits bounded, fp32 safe
        den += wgt;
        const uint4* xp = (const uint4*)(xl1b + (size_t)s * F1 + h * 16);
        uint4 u0 = xp[0], u1 = xp[1];
        float lo, hi;
        bf2f2(u0.x, &lo, &hi); acc[0] += wgt * lo;  acc[1] += wgt * hi;
        bf2f2(u0.y, &lo, &hi); acc[2] += wgt * lo;  acc[3] += wgt * hi;
        bf2f2(u0.z, &lo, &hi); acc[4] += wgt * lo;  acc[5] += wgt * hi;
        bf2f2(u0.w, &lo, &hi); acc[6] += wgt * lo;  acc[7] += wgt * hi;
        bf2f2(u1.x, &lo, &hi); acc[8] += wgt * lo;  acc[9] += wgt * hi;
        bf2f2(u1.y, &lo, &hi); acc[10] += wgt * lo; acc[11] += wgt * hi;
        bf2f2(u1.z, &lo, &hi); acc[12] += wgt * lo; acc[13] += wgt * hi;
        bf2f2(u1.w, &lo, &hi); acc[14] += wgt * lo; acc[15] += wgt * hi;
    }
    den += __shfl_xor(den, 16);
    den += __shfl_xor(den, 32);
    float inv = 1.f / (den + 1e-16f);
    #pragma unroll
    for (int c = 0; c < 16; c++) {
        acc[c] += __shfl_xor(acc[c], 16);
        acc[c] += __shfl_xor(acc[c], 32);
    }
    if (eg == 0) {
        #pragma unroll
        for (int q = 0; q < 8; q++) {
            float v0 = acc[2 * q] * inv + b1[h * 16 + 2 * q];
            float v1 = acc[2 * q + 1] * inv + b1[h * 16 + 2 * q + 1];
            v0 = v0 > 0.f ? v0 : expm1f(v0);   // ELU
            v1 = v1 > 0.f ? v1 : expm1f(v1);
            rowbuf[tid >> 6][h * 8 + q] =
                (uint32_t)f2bf1(v0) | ((uint32_t)f2bf1(v1) << 16);
        }
    }
    __syncthreads();
    // layer2 phase: 32 items (4 nodes x 8 heads2), 8 threads each over k-range
    int it = tid >> 3, sub = tid & 7;
    int nl = it >> 3, h2 = it & 7;
    int c0 = h2 * 3;
    float a0 = 0.f, a1 = 0.f, a2 = 0.f;
    #pragma unroll
    for (int m = 0; m < 16; m++) {
        int k = sub * 32 + m * 2;
        uint32_t u = rowbuf[nl][k >> 1];
        float lo, hi;
        bf2f2(u, &lo, &hi);
        a0 += lo * bf2f(W2s[c0][k])     + hi * bf2f(W2s[c0][k + 1]);
        a1 += lo * bf2f(W2s[c0 + 1][k]) + hi * bf2f(W2s[c0 + 1][k + 1]);
        a2 += lo * bf2f(W2s[c0 + 2][k]) + hi * bf2f(W2s[c0 + 2][k + 1]);
    }
    a0 += __shfl_xor(a0, 1); a0 += __shfl_xor(a0, 2); a0 += __shfl_xor(a0, 4);
    a1 += __shfl_xor(a1, 1); a1 += __shfl_xor(a1, 2); a1 += __shfl_xor(a1, 4);
    a2 += __shfl_xor(a2, 1); a2 += __shfl_xor(a2, 2); a2 += __shfl_xor(a2, 4);
    if (sub == 0) {
        int n = blockIdx.x * 4 + nl;
        int idx = n * 8 + h2;
        uint2 pk;
        pk.x = (uint32_t)f2bf1(a0) | ((uint32_t)f2bf1(a1) << 16);
        pk.y = (uint32_t)f2bf1(a2);
        *(uint2*)(xl2b + (size_t)idx * 4) = pk;
        asrc2[idx] = a0 * a_src2[h2 * 3 + 0] + a1 * a_src2[h2 * 3 + 1] + a2 * a_src2[h2 * 3 + 2];
        adst2[idx] = a0 * a_dst2[h2 * 3 + 0] + a1 * a_dst2[h2 * 3 + 1] + a2 * a_dst2[h2 * 3 + 2];
    }
}

// ---------------- aggregation layer 2 (wave per node, 4B CSR) ----------------
__global__ __launch_bounds__(256) void k_agg2(const int* __restrict__ rowptr,
        const uint32_t* __restrict__ csr,
        const uint16_t* __restrict__ xl2b, const float* __restrict__ asrc,
        const float* __restrict__ adst, const float* __restrict__ scalars,
        const float* __restrict__ b2, float* __restrict__ out) {
    int node = blockIdx.x * 4 + (threadIdx.x >> 6);
    int lane = threadIdx.x & 63;
    int eg = lane >> 3, h = lane & 7;
    int r0 = rowptr[node], r1 = rowptr[node + 1];
    float ad = adst[node * 8 + h];
    float wd = scalars[17 + h];
    float den = 0.f, a0 = 0.f, a1 = 0.f, a2 = 0.f;
    for (int j = r0 + eg; j < r1; j += 8) {
        uint32_t pk = csr[j];
        int s = (int)(pk & 0xFFFFu);
        float eav = __uint_as_float(pk & 0xFFFF0000u);
        float a = lrelu(asrc[s * 8 + h] + ad + eav * wd);
        float wgt = __expf(a);
        den += wgt;
        const uint2* xp = (const uint2*)(xl2b + ((size_t)s * 8 + h) * 4);
        uint2 u = xp[0];
        float x0, x1, x2, dummy;
        bf2f2(u.x, &x0, &x1);
        bf2f2(u.y, &x2, &dummy);
        a0 += wgt * x0;
        a1 += wgt * x1;
        a2 += wgt * x2;
    }
    den += __shfl_xor(den, 8); den += __shfl_xor(den, 16); den += __shfl_xor(den, 32);
    float inv = 1.f / (den + 1e-16f);
    a0 += __shfl_xor(a0, 8); a0 += __shfl_xor(a0, 16); a0 += __shfl_xor(a0, 32);
    a1 += __shfl_xor(a1, 8); a1 += __shfl_xor(a1, 16); a1 += __shfl_xor(a1, 32);
    a2 += __shfl_xor(a2, 8); a2 += __shfl_xor(a2, 16); a2 += __shfl_xor(a2, 32);
    a0 *= inv; a1 *= inv; a2 *= inv;
    a0 += __shfl_xor(a0, 1); a0 += __shfl_xor(a0, 2); a0 += __shfl_xor(a0, 4);
    a1 += __shfl_xor(a1, 1); a1 += __shfl_xor(a1, 2); a1 += __shfl_xor(a1, 4);
    a2 += __shfl_xor(a2, 1); a2 += __shfl_xor(a2, 2); a2 += __shfl_xor(a2, 4);
    if (lane == 0) {
        float v0 = a0 * 0.125f + b2[0];
        float v1 = a1 * 0.125f + b2[1];
        float v2 = a2 * 0.125f + b2[2];
        out[node * 3 + 0] = v0 > 0.f ? v0 : expm1f(v0);
        out[node * 3 + 1] = v1 > 0.f ? v1 : expm1f(v1);
        out[node * 3 + 2] = v2 > 0.f ? v2 : expm1f(v2);
    }
}

extern "C" void kernel_launch(void* const* d_in, const int* in_sizes, int n_in,
                              void* d_out, int out_size, void* d_ws, size_t ws_size,
                              hipStream_t stream) {
    const float* x       = (const float*)d_in[0];
    const int*   ei      = (const int*)d_in[1];
    const float* ea      = (const float*)d_in[2];
    const float* W1      = (const float*)d_in[3];
    const float* We1     = (const float*)d_in[4];
    const float* a_src1  = (const float*)d_in[5];
    const float* a_dst1  = (const float*)d_in[6];
    const float* a_edge1 = (const float*)d_in[7];
    const float* b1      = (const float*)d_in[8];
    const float* W2      = (const float*)d_in[9];
    const float* We2     = (const float*)d_in[10];
    const float* a_src2  = (const float*)d_in[11];
    const float* a_dst2  = (const float*)d_in[12];
    const float* a_edge2 = (const float*)d_in[13];
    const float* b2      = (const float*)d_in[14];
    float* out = (float*)d_out;

    char* ws = (char*)d_ws;
    size_t off = 0;
    auto alloc = [&](size_t nbytes) -> void* {
        void* p = ws + off;
        off = (off + nbytes + 255) & ~(size_t)255;
        return p;
    };
    uint16_t* xl1b  = (uint16_t*)alloc((size_t)N_NODES * F1 * 2);
    float* asrc1    = (float*)alloc((size_t)N_NODES * NH1 * 4);
    float* adst1    = (float*)alloc((size_t)N_NODES * NH1 * 4);
    uint16_t* xl2b  = (uint16_t*)alloc((size_t)N_NODES * 32 * 2);
    float* asrc2    = (float*)alloc((size_t)N_NODES * NH2 * 4);
    float* adst2    = (float*)alloc((size_t)N_NODES * NH2 * 4);
    int*   counts   = (int*)alloc((size_t)N_NODES * 4);
    int*   rowptr   = (int*)alloc((size_t)(N_NODES + 1) * 4);
    int*   cursor   = (int*)alloc((size_t)N_NODES * 4);
    int*   bsums    = (int*)alloc(64 * 4);
    uint32_t* csr   = (uint32_t*)alloc((size_t)N_TOT * 4);
    float* scalars  = (float*)alloc(128);
    float* part     = (float*)alloc(256 * 4);
    uint16_t* wht   = (uint16_t*)alloc((size_t)F1 * KP * 2);
    uint16_t* xh    = (uint16_t*)alloc((size_t)MPAD * KP * 2);

    hipMemsetAsync(counts, 0, (size_t)N_NODES * 4, stream);
    hipLaunchKernelGGL(k_pre, dim3(HIST_B + EASUM_B + CVT_B), dim3(256), 0, stream,
                       ei, ea, x, W1, counts, part, xh, wht);
    hipLaunchKernelGGL(k_scan1, dim3(50), dim3(1024), 0, stream,
                       counts, rowptr, bsums, We1, a_edge1, We2, a_edge2, part, scalars);
    hipLaunchKernelGGL(k_scan2, dim3(49), dim3(1024), 0, stream,
                       rowptr, cursor, bsums, scalars, csr);
    hipLaunchKernelGGL(k_scatter, dim3((N_EDGES + 255) / 256), dim3(256), 0, stream,
                       ei, ea, cursor, csr);
    hipLaunchKernelGGL(k_gemm1_mfma, dim3(MPAD / 64), dim3(256), 0, stream,
                       xh, wht, a_src1, a_dst1, xl1b, asrc1, adst1);
    hipLaunchKernelGGL(k_agg1, dim3(N_NODES / 4), dim3(256), 0, stream,
                       rowptr, csr, xl1b, asrc1, adst1, scalars, b1,
                       W2, a_src2, a_dst2, xl2b, asrc2, adst2);
    hipLaunchKernelGGL(k_agg2, dim3(N_NODES / 4), dim3(256), 0, stream,
                       rowptr, csr, xl2b, asrc2, adst2, scalars, b2, out);
}

// Round 14
// 272.752 us; speedup vs baseline: 1.2733x; 1.1218x over previous
//
#include <hip/hip_runtime.h>
#include <math.h>
#include <stdint.h>

#define N_NODES 50000
#define N_EDGES 800000
#define N_TOT   850000
#define IN_F    191
#define F1      256
#define NH1     16
#define NC1     16
#define F2      24
#define NH2     8
#define NC2     3
#define KP      192          // K padded to 6*32 (191 fits)
#define MPAD    50048        // 782*64
#define NCVT_X  (MPAD * 24)
#define NCVT_W  (F1 * 24)
#define HIST_B  3125
#define EASUM_B 256
#define CVT_B   ((NCVT_X + NCVT_W) / 256)   // 4716 exactly

typedef __attribute__((ext_vector_type(8))) short bf16x8;
typedef __attribute__((ext_vector_type(4))) float f32x4;

#define GLL16(g, s) __builtin_amdgcn_global_load_lds( \
    (const __attribute__((address_space(1))) void*)(g), \
    (__attribute__((address_space(3))) void*)(s), 16, 0, 0)

__device__ __forceinline__ float lrelu(float x) { return x > 0.f ? x : 0.2f * x; }

__device__ __forceinline__ uint16_t f2bf1(float f) {
    uint32_t u = __float_as_uint(f);
    return (uint16_t)((u + 0x7fffu + ((u >> 16) & 1u)) >> 16);
}
__device__ __forceinline__ void bf2f2(uint32_t u, float* lo, float* hi) {
    *lo = __uint_as_float(u << 16);
    *hi = __uint_as_float(u & 0xffff0000u);
}

// ---------------- fused pre-pass: {histogram | easum | cvt} by block range ----------------
__global__ void k_pre(const int* __restrict__ ei, const float* __restrict__ ea,
                      const float* __restrict__ x, const float* __restrict__ W1,
                      int* counts, float* __restrict__ part,
                      uint16_t* __restrict__ xh, uint16_t* __restrict__ wht) {
    int b = blockIdx.x, t = threadIdx.x;
    if (b < HIST_B) {
        int e = b * 256 + t;
        if (e < N_EDGES) atomicAdd(&counts[ei[N_EDGES + e]], 1);
    } else if (b < HIST_B + EASUM_B) {
        __shared__ float wsums[4];
        int eb = b - HIST_B;
        float v = 0.f;
        for (int e = eb * 256 + t; e < N_EDGES; e += 256 * 256) v += ea[e];
        #pragma unroll
        for (int off = 32; off >= 1; off >>= 1) v += __shfl_xor(v, off);
        if ((t & 63) == 0) wsums[t >> 6] = v;
        __syncthreads();
        if (t == 0) part[eb] = wsums[0] + wsums[1] + wsums[2] + wsums[3];
    } else {
        int idx = (b - HIST_B - EASUM_B) * 256 + t;
        if (idx < NCVT_X) {
            int row = idx / 24, kw = idx - row * 24;
            int k0 = kw * 8;
            uint16_t hv[8];
            #pragma unroll
            for (int j = 0; j < 8; j++) {
                int k = k0 + j;
                float v = (row < N_NODES && k < IN_F) ? x[(size_t)row * IN_F + k] : 0.f;
                hv[j] = f2bf1(v);
            }
            *(uint4*)(xh + (size_t)row * KP + k0) = *(const uint4*)hv;
        } else {
            int id2 = idx - NCVT_X;
            int col = id2 / 24, kw = id2 - col * 24;
            int k0 = kw * 8;
            uint16_t hv[8];
            #pragma unroll
            for (int j = 0; j < 8; j++) {
                int k = k0 + j;
                float v = (k < IN_F) ? W1[(size_t)k * F1 + col] : 0.f;
                hv[j] = f2bf1(v);
            }
            *(uint4*)(wht + (size_t)col * KP + k0) = *(const uint4*)hv;
        }
    }
}

// ---------------- scan stage 1 (blocks 0..48) + wedot (block 49) ----------------
__global__ __launch_bounds__(1024) void k_scan1(const int* __restrict__ counts,
        int* rowptr, int* bsums,
        const float* __restrict__ We1, const float* __restrict__ ae1,
        const float* __restrict__ We2, const float* __restrict__ ae2,
        const float* __restrict__ part, float* scalars) {
    int b = blockIdx.x, t = threadIdx.x;
    if (b == 49) {
        if (t < 64) {
            if (t < NH1) {
                float s = 0.f;
                for (int c = 0; c < NC1; c++) s += We1[t * NC1 + c] * ae1[t * NC1 + c];
                scalars[1 + t] = s;
            } else if (t < NH1 + NH2) {
                int h = t - NH1;
                float s = 0.f;
                for (int c = 0; c < NC2; c++) s += We2[h * NC2 + c] * ae2[h * NC2 + c];
                scalars[17 + h] = s;
            }
            float v = part[t * 4] + part[t * 4 + 1] + part[t * 4 + 2] + part[t * 4 + 3];
            #pragma unroll
            for (int off = 32; off >= 1; off >>= 1) v += __shfl_xor(v, off);
            if (t == 0) scalars[0] = v / (float)N_EDGES;   // ea_mean
        }
        return;
    }
    __shared__ int wsum[16];
    int lane = t & 63, w = t >> 6;
    int i = b * 1024 + t;
    int v = (i < N_NODES) ? counts[i] + 1 : 0;   // +1 = self loop
    int incl = v;
    #pragma unroll
    for (int off = 1; off < 64; off <<= 1) {
        int u = __shfl_up(incl, off);
        if (lane >= off) incl += u;
    }
    if (lane == 63) wsum[w] = incl;
    __syncthreads();
    int woff = 0;
    #pragma unroll
    for (int k = 0; k < 16; k++) woff += (k < w) ? wsum[k] : 0;
    if (i < N_NODES) rowptr[i] = woff + incl - v;
    if (t == 1023) bsums[b] = woff + incl;
}

// ---------------- scan stage 2: global prefix + SELF-LOOP placement ----------------
__global__ __launch_bounds__(1024) void k_scan2(int* rowptr, int* cursor,
                                                const int* __restrict__ bsums,
                                                const float* __restrict__ scalars,
                                                uint32_t* __restrict__ csr) {
    __shared__ int off_s;
    int b = blockIdx.x, t = threadIdx.x;
    if (t == 0) {
        int o = 0;
        for (int k = 0; k < b; k++) o += bsums[k];
        off_s = o;
        if (b == 48) rowptr[N_NODES] = o + bsums[48];
    }
    __syncthreads();
    uint32_t loop_ea = (uint32_t)f2bf1(scalars[0]) << 16;
    int i = b * 1024 + t;
    if (i < N_NODES) {
        int r = rowptr[i] + off_s;
        rowptr[i] = r;
        cursor[i] = r + 1;                       // edges go after the self loop
        csr[r] = (uint32_t)i | loop_ea;          // self loop placed here
    }
}

// ---------------- scatter real edges into 4B packed CSR (u16 src | bf16 ea) ----------------
__global__ void k_scatter(const int* __restrict__ ei, const float* __restrict__ ea,
                          int* cursor, uint32_t* __restrict__ csr) {
    int i = blockIdx.x * blockDim.x + threadIdx.x;
    if (i < N_EDGES) {
        int s = ei[i], d = ei[N_EDGES + i];
        int pos = atomicAdd(&cursor[d], 1);
        csr[pos] = (uint32_t)s | ((uint32_t)f2bf1(ea[i]) << 16);
    }
}

// ---------------- GEMM1 via MFMA: 64x256 tile (x read once) + fused alphas1 ----------------
__global__ __launch_bounds__(256) void k_gemm1_mfma(const uint16_t* __restrict__ xh,
        const uint16_t* __restrict__ wht, const float* __restrict__ a_src,
        const float* __restrict__ a_dst, uint16_t* __restrict__ xl1b,
        float* __restrict__ asrc1, float* __restrict__ adst1) {
    __shared__ uint16_t smem[64 * 256];     // 32 KiB
    uint16_t* ldsA = smem;                  // 4 frags * 512
    uint16_t* ldsB = smem + 4 * 512;        // 16 frags * 512
    const int t = threadIdx.x;
    const int l = t & 63, w = t >> 6;
    const int m0 = blockIdx.x * 64;
    const int lr = l & 15, lk = l >> 4;

    f32x4 acc[4][4];
    #pragma unroll
    for (int i = 0; i < 4; i++)
        #pragma unroll
        for (int j = 0; j < 4; j++)
            acc[i][j] = (f32x4){0.f, 0.f, 0.f, 0.f};

    for (int ks = 0; ks < 6; ks++) {
        const int kb = ks * 32 + lk * 8;
        #pragma unroll
        for (int ii = 0; ii < 5; ii++) {
            const int idx = w * 5 + ii;      // 0..19: 4 A-frags then 16 B-frags
            if (idx < 4) {
                const uint16_t* src = xh + (size_t)(m0 + idx * 16 + lr) * KP + kb;
                GLL16(src, ldsA + idx * 512);
            } else {
                const int g = idx - 4;
                const uint16_t* src = wht + (size_t)(g * 16 + lr) * KP + kb;
                GLL16(src, ldsB + g * 512);
            }
        }
        __syncthreads();
        bf16x8 ah[4];
        #pragma unroll
        for (int i = 0; i < 4; i++)
            ah[i] = *(const bf16x8*)(ldsA + (i * 64 + l) * 8);
        #pragma unroll
        for (int j = 0; j < 4; j++) {
            const int g = w * 4 + j;
            bf16x8 bh = *(const bf16x8*)(ldsB + (g * 64 + l) * 8);
            #pragma unroll
            for (int i = 0; i < 4; i++)
                acc[i][j] = __builtin_amdgcn_mfma_f32_16x16x32_bf16(ah[i], bh, acc[i][j], 0, 0, 0);
        }
        __syncthreads();
    }
    // epilogue: write xl1b (bf16) + stage rows into LDS for the alphas dot
    #pragma unroll
    for (int i = 0; i < 4; i++) {
        #pragma unroll
        for (int r = 0; r < 4; r++) {
            const int lrow = i * 16 + lk * 4 + r;
            const int gm = m0 + lrow;
            #pragma unroll
            for (int j = 0; j < 4; j++) {
                const int gn = (w * 4 + j) * 16 + lr;
                uint16_t bv = f2bf1(acc[i][j][r]);
                smem[lrow * 256 + gn] = bv;
                if (gm < N_NODES) xl1b[(size_t)gm * F1 + gn] = bv;
            }
        }
    }
    __syncthreads();
    // alphas: 64 rows x 16 heads = 1024 items, 4 per thread
    #pragma unroll
    for (int q = 0; q < 4; q++) {
        int item = q * 256 + t;
        int row = item >> 4, h = item & 15;
        int gm = m0 + row;
        if (gm < N_NODES) {
            const uint4* rp = (const uint4*)(smem + row * 256 + h * 16);
            uint4 u0 = rp[0], u1 = rp[1];
            uint32_t us[8] = {u0.x, u0.y, u0.z, u0.w, u1.x, u1.y, u1.z, u1.w};
            float as = 0.f, ad = 0.f;
            #pragma unroll
            for (int p = 0; p < 8; p++) {
                float lo, hi;
                bf2f2(us[p], &lo, &hi);
                as += lo * a_src[h * 16 + 2 * p] + hi * a_src[h * 16 + 2 * p + 1];
                ad += lo * a_dst[h * 16 + 2 * p] + hi * a_dst[h * 16 + 2 * p + 1];
            }
            asrc1[gm * 16 + h] = as;
            adst1[gm * 16 + h] = ad;
        }
    }
}

// ---------------- aggregation layer 1 (locked R8 form: 4 edge-groups x 32B/lane) ----------------
__global__ __launch_bounds__(256) void k_agg1(const int* __restrict__ rowptr,
        const uint32_t* __restrict__ csr,
        const uint16_t* __restrict__ xl1b, const float* __restrict__ asrc,
        const float* __restrict__ adst, const float* __restrict__ scalars,
        const float* __restrict__ b1, uint16_t* __restrict__ h1b) {
    int node = blockIdx.x * 4 + (threadIdx.x >> 6);
    int lane = threadIdx.x & 63;
    int eg = lane >> 4, h = lane & 15;
    int r0 = rowptr[node], r1 = rowptr[node + 1];
    float ad = adst[node * 16 + h];
    float wd = scalars[1 + h];
    float den = 0.f;
    float acc[16];
    #pragma unroll
    for (int c = 0; c < 16; c++) acc[c] = 0.f;
    for (int j = r0 + eg; j < r1; j += 4) {
        uint32_t pk = csr[j];
        int s = (int)(pk & 0xFFFFu);
        float eav = __uint_as_float(pk & 0xFFFF0000u);
        float a = lrelu(asrc[s * 16 + h] + ad + eav * wd);
        float wgt = __expf(a);           // no max-shift: logits bounded, fp32 safe
        den += wgt;
        const uint4* xp = (const uint4*)(xl1b + (size_t)s * F1 + h * 16);
        uint4 u0 = xp[0], u1 = xp[1];
        float lo, hi;
        bf2f2(u0.x, &lo, &hi); acc[0] += wgt * lo;  acc[1] += wgt * hi;
        bf2f2(u0.y, &lo, &hi); acc[2] += wgt * lo;  acc[3] += wgt * hi;
        bf2f2(u0.z, &lo, &hi); acc[4] += wgt * lo;  acc[5] += wgt * hi;
        bf2f2(u0.w, &lo, &hi); acc[6] += wgt * lo;  acc[7] += wgt * hi;
        bf2f2(u1.x, &lo, &hi); acc[8] += wgt * lo;  acc[9] += wgt * hi;
        bf2f2(u1.y, &lo, &hi); acc[10] += wgt * lo; acc[11] += wgt * hi;
        bf2f2(u1.z, &lo, &hi); acc[12] += wgt * lo; acc[13] += wgt * hi;
        bf2f2(u1.w, &lo, &hi); acc[14] += wgt * lo; acc[15] += wgt * hi;
    }
    den += __shfl_xor(den, 16);
    den += __shfl_xor(den, 32);
    float inv = 1.f / (den + 1e-16f);
    #pragma unroll
    for (int c = 0; c < 16; c++) {
        acc[c] += __shfl_xor(acc[c], 16);
        acc[c] += __shfl_xor(acc[c], 32);
    }
    if (eg == 0) {
        uint32_t pk[8];
        #pragma unroll
        for (int q = 0; q < 8; q++) {
            float v0 = acc[2 * q] * inv + b1[h * 16 + 2 * q];
            float v1 = acc[2 * q + 1] * inv + b1[h * 16 + 2 * q + 1];
            v0 = v0 > 0.f ? v0 : expm1f(v0);   // ELU
            v1 = v1 > 0.f ? v1 : expm1f(v1);
            pk[q] = (uint32_t)f2bf1(v0) | ((uint32_t)f2bf1(v1) << 16);
        }
        uint4* op = (uint4*)(h1b + (size_t)node * F1 + h * 16);
        op[0] = make_uint4(pk[0], pk[1], pk[2], pk[3]);
        op[1] = make_uint4(pk[4], pk[5], pk[6], pk[7]);
    }
}

// ---------------- fused layer2: xl2 = h1 @ W2 (+pad) AND alpha_src2/alpha_dst2 ----------------
__global__ __launch_bounds__(256) void k_layer2(const uint16_t* __restrict__ h1b,
        const float* __restrict__ W2, const float* __restrict__ a_src,
        const float* __restrict__ a_dst, uint16_t* __restrict__ xl2b,
        float* __restrict__ asrc, float* __restrict__ adst) {
    __shared__ float W2s[F2][258];   // [col][k], padded stride
    int t = threadIdx.x;
    for (int i = t; i < 256 * F2; i += 256) {
        int k = i / F2, c = i - k * F2;
        W2s[c][k] = W2[i];
    }
    __syncthreads();
    int idx = blockIdx.x * 256 + t;
    if (idx >= N_NODES * NH2) return;
    int n = idx >> 3, h = idx & 7;
    int c0 = h * 3;
    const uint4* hp = (const uint4*)(h1b + (size_t)n * F1);
    float a0 = 0.f, a1 = 0.f, a2 = 0.f;
    #pragma unroll 4
    for (int q = 0; q < 32; q++) {
        uint4 u = hp[q];
        float f[8];
        bf2f2(u.x, &f[0], &f[1]);
        bf2f2(u.y, &f[2], &f[3]);
        bf2f2(u.z, &f[4], &f[5]);
        bf2f2(u.w, &f[6], &f[7]);
        #pragma unroll
        for (int j = 0; j < 8; j++) {
            int k = q * 8 + j;
            a0 += f[j] * W2s[c0][k];
            a1 += f[j] * W2s[c0 + 1][k];
            a2 += f[j] * W2s[c0 + 2][k];
        }
    }
    uint2 pk;
    pk.x = (uint32_t)f2bf1(a0) | ((uint32_t)f2bf1(a1) << 16);
    pk.y = (uint32_t)f2bf1(a2);
    *(uint2*)(xl2b + (size_t)idx * 4) = pk;
    asrc[idx] = a0 * a_src[h * 3 + 0] + a1 * a_src[h * 3 + 1] + a2 * a_src[h * 3 + 2];
    adst[idx] = a0 * a_dst[h * 3 + 0] + a1 * a_dst[h * 3 + 1] + a2 * a_dst[h * 3 + 2];
}

// ---------------- aggregation layer 2 (wave per node, 4B CSR) ----------------
__global__ __launch_bounds__(256) void k_agg2(const int* __restrict__ rowptr,
        const uint32_t* __restrict__ csr,
        const uint16_t* __restrict__ xl2b, const float* __restrict__ asrc,
        const float* __restrict__ adst, const float* __restrict__ scalars,
        const float* __restrict__ b2, float* __restrict__ out) {
    int node = blockIdx.x * 4 + (threadIdx.x >> 6);
    int lane = threadIdx.x & 63;
    int eg = lane >> 3, h = lane & 7;
    int r0 = rowptr[node], r1 = rowptr[node + 1];
    float ad = adst[node * 8 + h];
    float wd = scalars[17 + h];
    float den = 0.f, a0 = 0.f, a1 = 0.f, a2 = 0.f;
    for (int j = r0 + eg; j < r1; j += 8) {
        uint32_t pk = csr[j];
        int s = (int)(pk & 0xFFFFu);
        float eav = __uint_as_float(pk & 0xFFFF0000u);
        float a = lrelu(asrc[s * 8 + h] + ad + eav * wd);
        float wgt = __expf(a);
        den += wgt;
        const uint2* xp = (const uint2*)(xl2b + ((size_t)s * 8 + h) * 4);
        uint2 u = xp[0];
        float x0, x1, x2, dummy;
        bf2f2(u.x, &x0, &x1);
        bf2f2(u.y, &x2, &dummy);
        a0 += wgt * x0;
        a1 += wgt * x1;
        a2 += wgt * x2;
    }
    den += __shfl_xor(den, 8); den += __shfl_xor(den, 16); den += __shfl_xor(den, 32);
    float inv = 1.f / (den + 1e-16f);
    a0 += __shfl_xor(a0, 8); a0 += __shfl_xor(a0, 16); a0 += __shfl_xor(a0, 32);
    a1 += __shfl_xor(a1, 8); a1 += __shfl_xor(a1, 16); a1 += __shfl_xor(a1, 32);
    a2 += __shfl_xor(a2, 8); a2 += __shfl_xor(a2, 16); a2 += __shfl_xor(a2, 32);
    a0 *= inv; a1 *= inv; a2 *= inv;
    a0 += __shfl_xor(a0, 1); a0 += __shfl_xor(a0, 2); a0 += __shfl_xor(a0, 4);
    a1 += __shfl_xor(a1, 1); a1 += __shfl_xor(a1, 2); a1 += __shfl_xor(a1, 4);
    a2 += __shfl_xor(a2, 1); a2 += __shfl_xor(a2, 2); a2 += __shfl_xor(a2, 4);
    if (lane == 0) {
        float v0 = a0 * 0.125f + b2[0];
        float v1 = a1 * 0.125f + b2[1];
        float v2 = a2 * 0.125f + b2[2];
        out[node * 3 + 0] = v0 > 0.f ? v0 : expm1f(v0);
        out[node * 3 + 1] = v1 > 0.f ? v1 : expm1f(v1);
        out[node * 3 + 2] = v2 > 0.f ? v2 : expm1f(v2);
    }
}

extern "C" void kernel_launch(void* const* d_in, const int* in_sizes, int n_in,
                              void* d_out, int out_size, void* d_ws, size_t ws_size,
                              hipStream_t stream) {
    const float* x       = (const float*)d_in[0];
    const int*   ei      = (const int*)d_in[1];
    const float* ea      = (const float*)d_in[2];
    const float* W1      = (const float*)d_in[3];
    const float* We1     = (const float*)d_in[4];
    const float* a_src1  = (const float*)d_in[5];
    const float* a_dst1  = (const float*)d_in[6];
    const float* a_edge1 = (const float*)d_in[7];
    const float* b1      = (const float*)d_in[8];
    const float* W2      = (const float*)d_in[9];
    const float* We2     = (const float*)d_in[10];
    const float* a_src2  = (const float*)d_in[11];
    const float* a_dst2  = (const float*)d_in[12];
    const float* a_edge2 = (const float*)d_in[13];
    const float* b2      = (const float*)d_in[14];
    float* out = (float*)d_out;

    char* ws = (char*)d_ws;
    size_t off = 0;
    auto alloc = [&](size_t nbytes) -> void* {
        void* p = ws + off;
        off = (off + nbytes + 255) & ~(size_t)255;
        return p;
    };
    uint16_t* xl1b  = (uint16_t*)alloc((size_t)N_NODES * F1 * 2);
    uint16_t* h1b   = (uint16_t*)alloc((size_t)N_NODES * F1 * 2);
    float* asrc1    = (float*)alloc((size_t)N_NODES * NH1 * 4);
    float* adst1    = (float*)alloc((size_t)N_NODES * NH1 * 4);
    uint16_t* xl2b  = (uint16_t*)alloc((size_t)N_NODES * 32 * 2);
    float* asrc2    = (float*)alloc((size_t)N_NODES * NH2 * 4);
    float* adst2    = (float*)alloc((size_t)N_NODES * NH2 * 4);
    int*   counts   = (int*)alloc((size_t)N_NODES * 4);
    int*   rowptr   = (int*)alloc((size_t)(N_NODES + 1) * 4);
    int*   cursor   = (int*)alloc((size_t)N_NODES * 4);
    int*   bsums    = (int*)alloc(64 * 4);
    uint32_t* csr   = (uint32_t*)alloc((size_t)N_TOT * 4);
    float* scalars  = (float*)alloc(128);
    float* part     = (float*)alloc(256 * 4);
    uint16_t* wht   = (uint16_t*)alloc((size_t)F1 * KP * 2);
    uint16_t* xh    = (uint16_t*)alloc((size_t)MPAD * KP * 2);

    hipMemsetAsync(counts, 0, (size_t)N_NODES * 4, stream);
    hipLaunchKernelGGL(k_pre, dim3(HIST_B + EASUM_B + CVT_B), dim3(256), 0, stream,
                       ei, ea, x, W1, counts, part, xh, wht);
    hipLaunchKernelGGL(k_scan1, dim3(50), dim3(1024), 0, stream,
                       counts, rowptr, bsums, We1, a_edge1, We2, a_edge2, part, scalars);
    hipLaunchKernelGGL(k_scan2, dim3(49), dim3(1024), 0, stream,
                       rowptr, cursor, bsums, scalars, csr);
    hipLaunchKernelGGL(k_scatter, dim3((N_EDGES + 255) / 256), dim3(256), 0, stream,
                       ei, ea, cursor, csr);
    hipLaunchKernelGGL(k_gemm1_mfma, dim3(MPAD / 64), dim3(256), 0, stream,
                       xh, wht, a_src1, a_dst1, xl1b, asrc1, adst1);
    hipLaunchKernelGGL(k_agg1, dim3(N_NODES / 4), dim3(256), 0, stream,
                       rowptr, csr, xl1b, asrc1, adst1, scalars, b1, h1b);
    hipLaunchKernelGGL(k_layer2, dim3((N_NODES * NH2 + 255) / 256), dim3(256), 0, stream,
                       h1b, W2, a_src2, a_dst2, xl2b, asrc2, adst2);
    hipLaunchKernelGGL(k_agg2, dim3(N_NODES / 4), dim3(256), 0, stream,
                       rowptr, csr, xl2b, asrc2, adst2, scalars, b2, out);
}